// Round 5
// baseline (257.750 us; speedup 1.0000x reference)
//
#include <hip/hip_runtime.h>
#include <hip/hip_bf16.h>
#include <stdint.h>

#define T_TOK 2048
#define HID   1024
#define FFN_  2048
#define NEXP  8
#define NPAIR 4096   // T_TOK * top_k(2)
#define MAXTILE 40   // sum over experts of ceil(cnt/128) <= 32+8

typedef __bf16 bf16;
typedef __bf16 bf16x8 __attribute__((ext_vector_type(8)));
typedef __bf16 bf16x4 __attribute__((ext_vector_type(4)));
typedef float  f32x4  __attribute__((ext_vector_type(4)));
typedef unsigned int u32;

// ---- workspace layout (bytes) ----
#define OFF_EXP   0                                   // int[9]
#define OFF_NT    64                                  // int[1]
#define OFF_TTE   128                                 // int[64] tile->expert
#define OFF_TTM   512                                 // int[64] tile->m0
#define OFF_TOK   1024                                // int[NPAIR]
#define OFF_WGT   (OFF_TOK + 16384)                   // float[NPAIR]
#define OFF_XG    65536                               // bf16 [NPAIR][HID]   : 8 MB
#define OFF_H1    (OFF_XG + (size_t)NPAIR*HID*2)      // bf16 [NPAIR][FFN_]  : 16 MB
#define OFF_WT    (OFF_H1 + (size_t)NPAIR*FFN_*2)     // transposed bf16 weights (phased)

// async global->LDS, 16B per lane (dest = wave-uniform base + lane*16)
__device__ __forceinline__ void gld16(const void* g, void* l) {
    __builtin_amdgcn_global_load_lds(
        (const __attribute__((address_space(1))) u32*)g,
        (__attribute__((address_space(3))) u32*)l, 16, 0, 0);
}

// ---------------- routing: stable counting sort of pairs by expert ----------
__global__ void route_kernel(const uint32_t* __restrict__ te_raw,
                             const float* __restrict__ top_w,
                             int* __restrict__ expert_off,
                             int* __restrict__ ntile_g,
                             int* __restrict__ tte, int* __restrict__ ttm,
                             int* __restrict__ tok, float* __restrict__ wgt)
{
    __shared__ int counts[NEXP];
    __shared__ int offs[NEXP + 1];
    __shared__ int is64_s;
    int tid = threadIdx.x;           // 512 threads = 8 waves, wave w owns expert w
    int wv = tid >> 6, lane = tid & 63;
    if (tid == 0) {
        int z = 1;
        for (int i = 0; i < 64; ++i) if (te_raw[2*i + 1] != 0u) { z = 0; break; }
        is64_s = z;                  // int64 data has zero high words
    }
    __syncthreads();
    int is64 = is64_s;
    int cnt = 0;
    for (int base = 0; base < NPAIR; base += 64) {
        int p = base + lane;
        int eid = is64 ? (int)te_raw[2*p] : (int)te_raw[p];
        unsigned long long m = __ballot(eid == wv);
        cnt += __popcll(m);
    }
    if (lane == 0) counts[wv] = cnt;
    __syncthreads();
    if (tid == 0) {
        int s = 0;
        for (int e2 = 0; e2 < NEXP; ++e2) { offs[e2] = s; expert_off[e2] = s; s += counts[e2]; }
        offs[NEXP] = s; expert_off[NEXP] = s;
        int nt = 0;
        for (int e2 = 0; e2 < NEXP; ++e2)
            for (int m = offs[e2]; m < offs[e2 + 1]; m += 128) { tte[nt] = e2; ttm[nt] = m; ++nt; }
        *ntile_g = nt;
    }
    __syncthreads();
    int off = offs[wv];
    for (int base = 0; base < NPAIR; base += 64) {
        int p = base + lane;
        int eid = is64 ? (int)te_raw[2*p] : (int)te_raw[p];
        unsigned long long m = __ballot(eid == wv);
        if (eid == wv) {
            int pre = __popcll(m & ((1ull << lane) - 1ull));
            int s = off + pre;
            tok[s] = p >> 1;
            wgt[s] = top_w[p];
        }
        off += __popcll(m);
    }
}

// ---------------- gather x rows -> bf16 -------------------------------------
__global__ void gather_kernel(const float* __restrict__ x,
                              const int* __restrict__ tok,
                              bf16* __restrict__ Xg)
{
    int p = blockIdx.x;
    int t = tok[p];
    const float4* src = (const float4*)(x + (size_t)t * HID);
    float4 v = src[threadIdx.x];
    bf16x4 o;
    o[0] = (bf16)v.x; o[1] = (bf16)v.y; o[2] = (bf16)v.z; o[3] = (bf16)v.w;
    *(bf16x4*)(Xg + (size_t)p * HID + threadIdx.x * 4) = o;
}

// ---------------- transpose+convert: f32 [R][C] -> bf16 [C][R] --------------
__global__ void __launch_bounds__(256)
transpose_bf16(const float* __restrict__ in, bf16* __restrict__ outT,
               int R, int C)
{
    __shared__ bf16 tile[64 * 66];
    int e = blockIdx.z;
    in   += (size_t)e * R * C;
    outT += (size_t)e * R * C;
    int r0 = blockIdx.y * 64, c0 = blockIdx.x * 64;
    int tid = threadIdx.x;
    int rr = tid >> 4, cc = (tid & 15) * 4;
    #pragma unroll
    for (int it = 0; it < 4; ++it) {
        int r = rr + it * 16;
        float4 v = *(const float4*)(in + (size_t)(r0 + r) * C + c0 + cc);
        union { bf16 h[2]; u32 w; } a, b;
        a.h[0] = (bf16)v.x; a.h[1] = (bf16)v.y;
        b.h[0] = (bf16)v.z; b.h[1] = (bf16)v.w;
        *(u32*)(tile + r * 66 + cc)     = a.w;
        *(u32*)(tile + r * 66 + cc + 2) = b.w;
    }
    __syncthreads();
    #pragma unroll
    for (int it = 0; it < 2; ++it) {
        int gg = it * 256 + tid;
        int f = gg >> 3, k8 = (gg & 7) * 8;
        bf16x8 o;
        #pragma unroll
        for (int j = 0; j < 8; ++j) o[j] = tile[(k8 + j) * 66 + f];
        *(bf16x8*)(outT + (size_t)(c0 + f) * R + r0 + k8) = o;
    }
}

// ---------------- GEMM1: H1 = silu(Xg@Wu) * (Xg@Wg) per expert ---------------
// tile 128(M) x 64(N) x 2 matrices, BK=64, double-buffered with COUNTED vmcnt
// (loads stay in flight across raw s_barrier), tile-table grid
__global__ void __launch_bounds__(256)
moe_upgate(const bf16* __restrict__ Xg,
           const bf16* __restrict__ wuT, const bf16* __restrict__ wgT,
           const int* __restrict__ expert_off, const int* __restrict__ ntile_g,
           const int* __restrict__ tte, const int* __restrict__ ttm,
           int eb, int gcnt, bf16* __restrict__ H1)
{
    int ty = blockIdx.y;
    if (ty >= *ntile_g) return;          // workgroup-uniform exit
    int e = tte[ty];
    if (e < eb || e >= eb + gcnt) return; // workgroup-uniform exit
    int m0 = ttm[ty];
    int p1 = expert_off[e + 1];
    int n0 = blockIdx.x * 64;
    __shared__ bf16 As [2][128 * 64];    // 32 KB
    __shared__ bf16 Bus[2][64 * 64];     // 16 KB
    __shared__ bf16 Bgs[2][64 * 64];     // 16 KB -> 64 KB, 2 blocks/CU
    const bf16* wu = wuT + (size_t)(e - eb) * (HID * FFN_);
    const bf16* wg = wgT + (size_t)(e - eb) * (HID * FFN_);
    int tid = threadIdx.x, lane = tid & 63, wv = tid >> 6;
    int wm = wv >> 1, wn = wv & 1;
    int l16 = lane & 15, lhi = lane >> 4;
    f32x4 accU[4][2] = {};
    f32x4 accG[4][2] = {};

    auto stage = [&](int b, int k0) {    // 8 gld16 per thread
        #pragma unroll
        for (int c = 0; c < 4; ++c) {
            int g = c * 256 + tid;
            int r = g >> 3, pos = g & 7;
            int gr = m0 + r; if (gr >= p1) gr = p1 - 1;
            int gsrc = pos ^ (r & 7);
            gld16(Xg + (size_t)gr * HID + k0 + gsrc * 8, (char*)As[b] + g * 16);
        }
        #pragma unroll
        for (int c = 0; c < 2; ++c) {
            int g = c * 256 + tid;
            int f = g >> 3, pos = g & 7;
            int gsrc = pos ^ (f & 7);
            size_t so = (size_t)(n0 + f) * HID + k0 + gsrc * 8;
            gld16(wu + so, (char*)Bus[b] + g * 16);
            gld16(wg + so, (char*)Bgs[b] + g * 16);
        }
    };

    stage(0, 0);                         // tile 0 in flight (8 outstanding)
    for (int t = 0; t < HID / 64; ++t) {
        int cur = t & 1;
        // barrier 1: all waves done reading the buffer we are about to overwrite
        __builtin_amdgcn_s_barrier();
        if (t + 1 < HID / 64) {
            stage(cur ^ 1, (t + 1) * 64);            // +8 -> 16 outstanding
            asm volatile("s_waitcnt vmcnt(8)" ::: "memory");  // tile t landed
        } else {
            asm volatile("s_waitcnt vmcnt(0)" ::: "memory");
        }
        // barrier 2: every wave's share of tile t is in LDS
        __builtin_amdgcn_s_barrier();
        #pragma unroll
        for (int ks = 0; ks < 2; ++ks) {
            bf16x8 af[4];
            #pragma unroll
            for (int fm = 0; fm < 4; ++fm) {
                int r = wm * 64 + fm * 16 + l16;
                int gpos = (ks * 4 + lhi) ^ (r & 7);
                af[fm] = *(const bf16x8*)((char*)As[cur] + r * 128 + gpos * 16);
            }
            #pragma unroll
            for (int fn = 0; fn < 2; ++fn) {
                int fr = wn * 32 + fn * 16 + l16;
                int gpos = (ks * 4 + lhi) ^ (fr & 7);
                bf16x8 bu = *(const bf16x8*)((char*)Bus[cur] + fr * 128 + gpos * 16);
                bf16x8 bg = *(const bf16x8*)((char*)Bgs[cur] + fr * 128 + gpos * 16);
                #pragma unroll
                for (int fm = 0; fm < 4; ++fm) {
                    accU[fm][fn] = __builtin_amdgcn_mfma_f32_16x16x32_bf16(af[fm], bu, accU[fm][fn], 0, 0, 0);
                    accG[fm][fn] = __builtin_amdgcn_mfma_f32_16x16x32_bf16(af[fm], bg, accG[fm][fn], 0, 0, 0);
                }
            }
        }
    }
    #pragma unroll
    for (int fm = 0; fm < 4; ++fm)
    #pragma unroll
    for (int fn = 0; fn < 2; ++fn)
    #pragma unroll
    for (int rg = 0; rg < 4; ++rg) {
        int r = m0 + wm * 64 + fm * 16 + lhi * 4 + rg;
        if (r < p1) {
            float u = accU[fm][fn][rg], g = accG[fm][fn][rg];
            float h = (u / (1.f + __expf(-u))) * g;
            int fc = n0 + wn * 32 + fn * 16 + l16;
            H1[(size_t)r * FFN_ + fc] = (bf16)h;
        }
    }
}

// ---------------- GEMM2: out += (H1 @ Wdown) * wgt (atomic, 2 adds/elem) ----
__global__ void __launch_bounds__(256)
moe_down(const bf16* __restrict__ H1, const bf16* __restrict__ wdT,
         const int* __restrict__ expert_off, const int* __restrict__ ntile_g,
         const int* __restrict__ tte, const int* __restrict__ ttm,
         int eb, int gcnt,
         const int* __restrict__ tok, const float* __restrict__ wgt,
         float* __restrict__ out)
{
    int ty = blockIdx.y;
    if (ty >= *ntile_g) return;
    int e = tte[ty];
    if (e < eb || e >= eb + gcnt) return;
    int m0 = ttm[ty];
    int p1 = expert_off[e + 1];
    int n0 = blockIdx.x * 64;
    __shared__ bf16 As[2][128 * 64];     // 32 KB
    __shared__ bf16 Bs[2][64 * 64];      // 16 KB -> 48 KB, 3 blocks/CU
    __shared__ float wgt_s[128];
    __shared__ int   tok_s[128];
    const bf16* wd = wdT + (size_t)(e - eb) * (FFN_ * HID);
    int tid = threadIdx.x, lane = tid & 63, wv = tid >> 6;
    int wm = wv >> 1, wn = wv & 1;
    int l16 = lane & 15, lhi = lane >> 4;
    if (tid < 128) {
        int r = m0 + tid;
        if (r < p1) { wgt_s[tid] = wgt[r]; tok_s[tid] = tok[r]; }
        else        { wgt_s[tid] = 0.f;    tok_s[tid] = 0; }
    }
    __syncthreads();                     // wgt_s visible before pipeline starts
    f32x4 acc[4][2] = {};

    auto stage = [&](int b, int k0) {    // 6 gld16 per thread
        #pragma unroll
        for (int c = 0; c < 4; ++c) {
            int g = c * 256 + tid;
            int r = g >> 3, pos = g & 7;
            int gr = m0 + r; if (gr >= p1) gr = p1 - 1;
            int gsrc = pos ^ (r & 7);
            gld16(H1 + (size_t)gr * FFN_ + k0 + gsrc * 8, (char*)As[b] + g * 16);
        }
        #pragma unroll
        for (int c = 0; c < 2; ++c) {
            int g = c * 256 + tid;
            int f = g >> 3, pos = g & 7;
            int gsrc = pos ^ (f & 7);
            gld16(wd + (size_t)(n0 + f) * FFN_ + k0 + gsrc * 8, (char*)Bs[b] + g * 16);
        }
    };

    stage(0, 0);
    for (int t = 0; t < FFN_ / 64; ++t) {
        int cur = t & 1;
        __builtin_amdgcn_s_barrier();
        if (t + 1 < FFN_ / 64) {
            stage(cur ^ 1, (t + 1) * 64);
            asm volatile("s_waitcnt vmcnt(6)" ::: "memory");
        } else {
            asm volatile("s_waitcnt vmcnt(0)" ::: "memory");
        }
        __builtin_amdgcn_s_barrier();
        #pragma unroll
        for (int ks = 0; ks < 2; ++ks) {
            bf16x8 af[4];
            #pragma unroll
            for (int fm = 0; fm < 4; ++fm) {
                int r = wm * 64 + fm * 16 + l16;
                int gpos = (ks * 4 + lhi) ^ (r & 7);
                af[fm] = *(const bf16x8*)((char*)As[cur] + r * 128 + gpos * 16);
            }
            #pragma unroll
            for (int fn = 0; fn < 2; ++fn) {
                int fr = wn * 32 + fn * 16 + l16;
                int gpos = (ks * 4 + lhi) ^ (fr & 7);
                bf16x8 bd = *(const bf16x8*)((char*)Bs[cur] + fr * 128 + gpos * 16);
                #pragma unroll
                for (int fm = 0; fm < 4; ++fm)
                    acc[fm][fn] = __builtin_amdgcn_mfma_f32_16x16x32_bf16(af[fm], bd, acc[fm][fn], 0, 0, 0);
            }
        }
    }
    #pragma unroll
    for (int fm = 0; fm < 4; ++fm)
    #pragma unroll
    for (int fn = 0; fn < 2; ++fn)
    #pragma unroll
    for (int rg = 0; rg < 4; ++rg) {
        int rl = wm * 64 + fm * 16 + lhi * 4 + rg;
        if (m0 + rl < p1) {
            float v = acc[fm][fn][rg] * wgt_s[rl];
            atomicAdd(out + (size_t)tok_s[rl] * HID + n0 + wn * 32 + fn * 16 + l16, v);
        }
    }
}

extern "C" void kernel_launch(void* const* d_in, const int* in_sizes, int n_in,
                              void* d_out, int out_size, void* d_ws, size_t ws_size,
                              hipStream_t stream)
{
    const float*    x      = (const float*)d_in[0];
    const float*    top_w  = (const float*)d_in[2];
    const uint32_t* te     = (const uint32_t*)d_in[3];
    const float*    w_up   = (const float*)d_in[4];
    const float*    w_gate = (const float*)d_in[5];
    const float*    w_down = (const float*)d_in[6];
    float* out = (float*)d_out;
    char*  ws  = (char*)d_ws;

    int*   expert_off = (int*)(ws + OFF_EXP);
    int*   ntile_g    = (int*)(ws + OFF_NT);
    int*   tte        = (int*)(ws + OFF_TTE);
    int*   ttm        = (int*)(ws + OFF_TTM);
    int*   tok        = (int*)(ws + OFF_TOK);
    float* wgt        = (float*)(ws + OFF_WGT);
    bf16*  Xg         = (bf16*)(ws + OFF_XG);
    bf16*  H1         = (bf16*)(ws + OFF_H1);
    bf16*  WT         = (bf16*)(ws + OFF_WT);

    size_t wtcap = ws_size > (size_t)OFF_WT ? ws_size - (size_t)OFF_WT : 0;
    size_t perexp = (size_t)HID * FFN_ * 2;           // 4 MB bf16 per expert per matrix
    // cap groups at 4 experts so transposed weights stay L3-resident for the GEMM
    int g1 = (int)(wtcap / (2 * perexp));
    g1 = g1 >= 4 ? 4 : g1 >= 2 ? 2 : 1;
    int g2 = (int)(wtcap / perexp);
    g2 = g2 >= 4 ? 4 : g2 >= 2 ? 2 : 1;

    hipMemsetAsync(out, 0, (size_t)out_size * sizeof(float), stream);
    hipLaunchKernelGGL(route_kernel, dim3(1), dim3(512), 0, stream,
                       te, top_w, expert_off, ntile_g, tte, ttm, tok, wgt);
    hipLaunchKernelGGL(gather_kernel, dim3(NPAIR), dim3(256), 0, stream,
                       x, tok, Xg);

    for (int eb = 0; eb < NEXP; eb += g1) {
        bf16* wuT = WT;
        bf16* wgT = WT + (size_t)g1 * HID * FFN_;
        hipLaunchKernelGGL(transpose_bf16, dim3(FFN_ / 64, HID / 64, g1), dim3(256), 0, stream,
                           w_up + (size_t)eb * HID * FFN_, wuT, HID, FFN_);
        hipLaunchKernelGGL(transpose_bf16, dim3(FFN_ / 64, HID / 64, g1), dim3(256), 0, stream,
                           w_gate + (size_t)eb * HID * FFN_, wgT, HID, FFN_);
        hipLaunchKernelGGL(moe_upgate, dim3(FFN_ / 64, MAXTILE), dim3(256), 0, stream,
                           Xg, wuT, wgT, expert_off, ntile_g, tte, ttm, eb, g1, H1);
    }
    for (int eb = 0; eb < NEXP; eb += g2) {
        hipLaunchKernelGGL(transpose_bf16, dim3(HID / 64, FFN_ / 64, g2), dim3(256), 0, stream,
                           w_down + (size_t)eb * FFN_ * HID, WT, FFN_, HID);
        hipLaunchKernelGGL(moe_down, dim3(HID / 64, MAXTILE), dim3(256), 0, stream,
                           H1, WT, expert_off, ntile_g, tte, ttm, eb, g2, tok, wgt, out);
    }
}

// Round 6
// 195.426 us; speedup vs baseline: 1.3189x; 1.3189x over previous
//
#include <hip/hip_runtime.h>
#include <hip/hip_bf16.h>
#include <stdint.h>

#define T_TOK 2048
#define HID   1024
#define FFN_  2048
#define NEXP  8
#define NPAIR 4096   // T_TOK * top_k(2)
#define MAXTILE 40   // sum over experts of ceil(cnt/128) <= 32+8

typedef __bf16 bf16;
typedef __bf16 bf16x8 __attribute__((ext_vector_type(8)));
typedef __bf16 bf16x4 __attribute__((ext_vector_type(4)));
typedef float  f32x4  __attribute__((ext_vector_type(4)));
typedef unsigned int u32;

// ---- workspace layout (bytes) ----
#define OFF_EXP   0                                   // int[9]
#define OFF_NT    64                                  // int[1]
#define OFF_TTE   128                                 // int[64] tile->expert
#define OFF_TTM   512                                 // int[64] tile->m0
#define OFF_TOK   1024                                // int[NPAIR]
#define OFF_WGT   (OFF_TOK + 16384)                   // float[NPAIR]
#define OFF_XG    65536                               // bf16 [NPAIR][HID]   : 8 MB
#define OFF_H1    (OFF_XG + (size_t)NPAIR*HID*2)      // bf16 [NPAIR][FFN_]  : 16 MB
#define OFF_WT    (OFF_H1 + (size_t)NPAIR*FFN_*2)     // transposed bf16 weights (phased)

// async global->LDS, 16B per lane (dest = wave-uniform base + lane*16)
__device__ __forceinline__ void gld16(const void* g, void* l) {
    __builtin_amdgcn_global_load_lds(
        (const __attribute__((address_space(1))) u32*)g,
        (__attribute__((address_space(3))) u32*)l, 16, 0, 0);
}

// ---------------- routing: stable counting sort of pairs by expert ----------
__global__ void route_kernel(const uint32_t* __restrict__ te_raw,
                             const float* __restrict__ top_w,
                             int* __restrict__ expert_off,
                             int* __restrict__ ntile_g,
                             int* __restrict__ tte, int* __restrict__ ttm,
                             int* __restrict__ tok, float* __restrict__ wgt)
{
    __shared__ int counts[NEXP];
    __shared__ int offs[NEXP + 1];
    __shared__ int is64_s;
    int tid = threadIdx.x;           // 512 threads = 8 waves, wave w owns expert w
    int wv = tid >> 6, lane = tid & 63;
    if (tid == 0) {
        int z = 1;
        for (int i = 0; i < 64; ++i) if (te_raw[2*i + 1] != 0u) { z = 0; break; }
        is64_s = z;                  // int64 data has zero high words
    }
    __syncthreads();
    int is64 = is64_s;
    int cnt = 0;
    for (int base = 0; base < NPAIR; base += 64) {
        int p = base + lane;
        int eid = is64 ? (int)te_raw[2*p] : (int)te_raw[p];
        unsigned long long m = __ballot(eid == wv);
        cnt += __popcll(m);
    }
    if (lane == 0) counts[wv] = cnt;
    __syncthreads();
    if (tid == 0) {
        int s = 0;
        for (int e2 = 0; e2 < NEXP; ++e2) { offs[e2] = s; expert_off[e2] = s; s += counts[e2]; }
        offs[NEXP] = s; expert_off[NEXP] = s;
        int nt = 0;
        for (int e2 = 0; e2 < NEXP; ++e2)
            for (int m = offs[e2]; m < offs[e2 + 1]; m += 128) { tte[nt] = e2; ttm[nt] = m; ++nt; }
        *ntile_g = nt;
    }
    __syncthreads();
    int off = offs[wv];
    for (int base = 0; base < NPAIR; base += 64) {
        int p = base + lane;
        int eid = is64 ? (int)te_raw[2*p] : (int)te_raw[p];
        unsigned long long m = __ballot(eid == wv);
        if (eid == wv) {
            int pre = __popcll(m & ((1ull << lane) - 1ull));
            int s = off + pre;
            tok[s] = p >> 1;
            wgt[s] = top_w[p];
        }
        off += __popcll(m);
    }
}

// ---------------- gather x rows -> bf16 -------------------------------------
__global__ void gather_kernel(const float* __restrict__ x,
                              const int* __restrict__ tok,
                              bf16* __restrict__ Xg)
{
    int p = blockIdx.x;
    int t = tok[p];
    const float4* src = (const float4*)(x + (size_t)t * HID);
    float4 v = src[threadIdx.x];
    bf16x4 o;
    o[0] = (bf16)v.x; o[1] = (bf16)v.y; o[2] = (bf16)v.z; o[3] = (bf16)v.w;
    *(bf16x4*)(Xg + (size_t)p * HID + threadIdx.x * 4) = o;
}

// ---------------- transpose+convert: f32 [R][C] -> bf16 [C][R] --------------
// two source tensors in one launch (z < nz1 -> in1, else in2)
__global__ void __launch_bounds__(256)
transpose_bf16_2(const float* __restrict__ in1, bf16* __restrict__ out1,
                 const float* __restrict__ in2, bf16* __restrict__ out2,
                 int nz1, int R, int C)
{
    __shared__ bf16 tile[64 * 66];
    int z = blockIdx.z;
    const float* in = (z < nz1) ? in1 : in2;
    bf16* outT      = (z < nz1) ? out1 : out2;
    int e = (z < nz1) ? z : z - nz1;
    in   += (size_t)e * R * C;
    outT += (size_t)e * R * C;
    int r0 = blockIdx.y * 64, c0 = blockIdx.x * 64;
    int tid = threadIdx.x;
    int rr = tid >> 4, cc = (tid & 15) * 4;
    #pragma unroll
    for (int it = 0; it < 4; ++it) {
        int r = rr + it * 16;
        float4 v = *(const float4*)(in + (size_t)(r0 + r) * C + c0 + cc);
        union { bf16 h[2]; u32 w; } a, b;
        a.h[0] = (bf16)v.x; a.h[1] = (bf16)v.y;
        b.h[0] = (bf16)v.z; b.h[1] = (bf16)v.w;
        *(u32*)(tile + r * 66 + cc)     = a.w;
        *(u32*)(tile + r * 66 + cc + 2) = b.w;
    }
    __syncthreads();
    #pragma unroll
    for (int it = 0; it < 2; ++it) {
        int gg = it * 256 + tid;
        int f = gg >> 3, k8 = (gg & 7) * 8;
        bf16x8 o;
        #pragma unroll
        for (int j = 0; j < 8; ++j) o[j] = tile[(k8 + j) * 66 + f];
        *(bf16x8*)(outT + (size_t)(c0 + f) * R + r0 + k8) = o;
    }
}

// ---------------- GEMM1: H1 = silu(Xg@Wu) * (Xg@Wg) per expert ---------------
// tile 128(M) x 64(N) x 2 matrices, BK=64, single-buffer (m97 structure),
// tile-table grid, ALL loop-invariant addresses hoisted out of the K-loop
__global__ void __launch_bounds__(256)
moe_upgate(const bf16* __restrict__ Xg,
           const bf16* __restrict__ wuT, const bf16* __restrict__ wgT,
           const int* __restrict__ expert_off, const int* __restrict__ ntile_g,
           const int* __restrict__ tte, const int* __restrict__ ttm,
           int eb, int gcnt, bf16* __restrict__ H1)
{
    int ty = blockIdx.y;
    if (ty >= *ntile_g) return;
    int e = tte[ty];
    if (e < eb || e >= eb + gcnt) return;
    int m0 = ttm[ty];
    int p1 = expert_off[e + 1];
    int n0 = blockIdx.x * 64;
    __shared__ bf16 As [128 * 64];   // 16 KB
    __shared__ bf16 Bus[64 * 64];    // 8 KB
    __shared__ bf16 Bgs[64 * 64];    // 8 KB -> 32 KB total
    const bf16* wu = wuT + (size_t)(e - eb) * (HID * FFN_);
    const bf16* wg = wgT + (size_t)(e - eb) * (HID * FFN_);
    int tid = threadIdx.x, lane = tid & 63, wv = tid >> 6;
    int wm = wv >> 1, wn = wv & 1;
    int l16 = lane & 15, lhi = lane >> 4;
    f32x4 accU[4][2] = {};
    f32x4 accG[4][2] = {};

    // ---- hoisted staging pointers (advance +64 elems = +128B per K-step) ----
    const bf16* aptr[4]; u32 alds[4];
    #pragma unroll
    for (int c = 0; c < 4; ++c) {
        int g = c * 256 + tid;
        int r = g >> 3, pos = g & 7;
        int gr = m0 + r; if (gr >= p1) gr = p1 - 1;
        int gsrc = pos ^ (r & 7);
        aptr[c] = Xg + (size_t)gr * HID + gsrc * 8;
        alds[c] = g * 16;
    }
    const bf16* buptr[2]; const bf16* bgptr[2]; u32 blds[2];
    #pragma unroll
    for (int c = 0; c < 2; ++c) {
        int g = c * 256 + tid;
        int f = g >> 3, pos = g & 7;
        int gsrc = pos ^ (f & 7);
        size_t so = (size_t)(n0 + f) * HID + gsrc * 8;
        buptr[c] = wu + so;
        bgptr[c] = wg + so;
        blds[c] = g * 16;
    }
    // ---- hoisted LDS fragment-read byte offsets (K-invariant) ----
    u32 aro[2][4], bro[2][2];
    #pragma unroll
    for (int ks = 0; ks < 2; ++ks) {
        #pragma unroll
        for (int fm = 0; fm < 4; ++fm) {
            int r = wm * 64 + fm * 16 + l16;
            aro[ks][fm] = r * 128 + ((u32)((ks * 4 + lhi) ^ (r & 7))) * 16;
        }
        #pragma unroll
        for (int fn = 0; fn < 2; ++fn) {
            int fr = wn * 32 + fn * 16 + l16;
            bro[ks][fn] = fr * 128 + ((u32)((ks * 4 + lhi) ^ (fr & 7))) * 16;
        }
    }

    for (int t = 0; t < HID / 64; ++t) {
        #pragma unroll
        for (int c = 0; c < 4; ++c) { gld16(aptr[c], (char*)As + alds[c]); aptr[c] += 64; }
        #pragma unroll
        for (int c = 0; c < 2; ++c) {
            gld16(buptr[c], (char*)Bus + blds[c]); buptr[c] += 64;
            gld16(bgptr[c], (char*)Bgs + blds[c]); bgptr[c] += 64;
        }
        __syncthreads();
        #pragma unroll
        for (int ks = 0; ks < 2; ++ks) {
            bf16x8 af[4];
            #pragma unroll
            for (int fm = 0; fm < 4; ++fm)
                af[fm] = *(const bf16x8*)((char*)As + aro[ks][fm]);
            #pragma unroll
            for (int fn = 0; fn < 2; ++fn) {
                bf16x8 bu = *(const bf16x8*)((char*)Bus + bro[ks][fn]);
                bf16x8 bg = *(const bf16x8*)((char*)Bgs + bro[ks][fn]);
                #pragma unroll
                for (int fm = 0; fm < 4; ++fm) {
                    accU[fm][fn] = __builtin_amdgcn_mfma_f32_16x16x32_bf16(af[fm], bu, accU[fm][fn], 0, 0, 0);
                    accG[fm][fn] = __builtin_amdgcn_mfma_f32_16x16x32_bf16(af[fm], bg, accG[fm][fn], 0, 0, 0);
                }
            }
        }
        __syncthreads();
    }
    #pragma unroll
    for (int fm = 0; fm < 4; ++fm)
    #pragma unroll
    for (int fn = 0; fn < 2; ++fn)
    #pragma unroll
    for (int rg = 0; rg < 4; ++rg) {
        int r = m0 + wm * 64 + fm * 16 + lhi * 4 + rg;
        if (r < p1) {
            float u = accU[fm][fn][rg], g = accG[fm][fn][rg];
            float h = (u / (1.f + __expf(-u))) * g;
            int fc = n0 + wn * 32 + fn * 16 + l16;
            H1[(size_t)r * FFN_ + fc] = (bf16)h;
        }
    }
}

// ---------------- GEMM2: out += (H1 @ Wdown) * wgt (atomic, 2 adds/elem) ----
__global__ void __launch_bounds__(256)
moe_down(const bf16* __restrict__ H1, const bf16* __restrict__ wdT,
         const int* __restrict__ expert_off, const int* __restrict__ ntile_g,
         const int* __restrict__ tte, const int* __restrict__ ttm,
         int eb, int gcnt,
         const int* __restrict__ tok, const float* __restrict__ wgt,
         float* __restrict__ out)
{
    int ty = blockIdx.y;
    if (ty >= *ntile_g) return;
    int e = tte[ty];
    if (e < eb || e >= eb + gcnt) return;
    int m0 = ttm[ty];
    int p1 = expert_off[e + 1];
    int n0 = blockIdx.x * 64;
    __shared__ bf16 As[128 * 64];    // 16 KB
    __shared__ bf16 Bs [64 * 64];    // 8 KB -> 24 KB total
    __shared__ float wgt_s[128];
    __shared__ int   tok_s[128];
    const bf16* wd = wdT + (size_t)(e - eb) * (FFN_ * HID);
    int tid = threadIdx.x, lane = tid & 63, wv = tid >> 6;
    int wm = wv >> 1, wn = wv & 1;
    int l16 = lane & 15, lhi = lane >> 4;
    if (tid < 128) {
        int r = m0 + tid;
        if (r < p1) { wgt_s[tid] = wgt[r]; tok_s[tid] = tok[r]; }
        else        { wgt_s[tid] = 0.f;    tok_s[tid] = 0; }
    }
    f32x4 acc[4][2] = {};

    const bf16* aptr[4]; u32 alds[4];
    #pragma unroll
    for (int c = 0; c < 4; ++c) {
        int g = c * 256 + tid;
        int r = g >> 3, pos = g & 7;
        int gr = m0 + r; if (gr >= p1) gr = p1 - 1;
        int gsrc = pos ^ (r & 7);
        aptr[c] = H1 + (size_t)gr * FFN_ + gsrc * 8;
        alds[c] = g * 16;
    }
    const bf16* bptr[2]; u32 blds[2];
    #pragma unroll
    for (int c = 0; c < 2; ++c) {
        int g = c * 256 + tid;
        int f = g >> 3, pos = g & 7;
        int gsrc = pos ^ (f & 7);
        bptr[c] = wd + (size_t)(n0 + f) * FFN_ + gsrc * 8;
        blds[c] = g * 16;
    }
    u32 aro[2][4], bro[2][2];
    #pragma unroll
    for (int ks = 0; ks < 2; ++ks) {
        #pragma unroll
        for (int fm = 0; fm < 4; ++fm) {
            int r = wm * 64 + fm * 16 + l16;
            aro[ks][fm] = r * 128 + ((u32)((ks * 4 + lhi) ^ (r & 7))) * 16;
        }
        #pragma unroll
        for (int fn = 0; fn < 2; ++fn) {
            int fr = wn * 32 + fn * 16 + l16;
            bro[ks][fn] = fr * 128 + ((u32)((ks * 4 + lhi) ^ (fr & 7))) * 16;
        }
    }

    for (int t = 0; t < FFN_ / 64; ++t) {
        #pragma unroll
        for (int c = 0; c < 4; ++c) { gld16(aptr[c], (char*)As + alds[c]); aptr[c] += 64; }
        #pragma unroll
        for (int c = 0; c < 2; ++c) { gld16(bptr[c], (char*)Bs + blds[c]); bptr[c] += 64; }
        __syncthreads();
        #pragma unroll
        for (int ks = 0; ks < 2; ++ks) {
            bf16x8 af[4];
            #pragma unroll
            for (int fm = 0; fm < 4; ++fm)
                af[fm] = *(const bf16x8*)((char*)As + aro[ks][fm]);
            #pragma unroll
            for (int fn = 0; fn < 2; ++fn) {
                bf16x8 bd = *(const bf16x8*)((char*)Bs + bro[ks][fn]);
                #pragma unroll
                for (int fm = 0; fm < 4; ++fm)
                    acc[fm][fn] = __builtin_amdgcn_mfma_f32_16x16x32_bf16(af[fm], bd, acc[fm][fn], 0, 0, 0);
            }
        }
        __syncthreads();
    }
    #pragma unroll
    for (int fm = 0; fm < 4; ++fm)
    #pragma unroll
    for (int fn = 0; fn < 2; ++fn)
    #pragma unroll
    for (int rg = 0; rg < 4; ++rg) {
        int rl = wm * 64 + fm * 16 + lhi * 4 + rg;
        if (m0 + rl < p1) {
            float v = acc[fm][fn][rg] * wgt_s[rl];
            atomicAdd(out + (size_t)tok_s[rl] * HID + n0 + wn * 32 + fn * 16 + l16, v);
        }
    }
}

extern "C" void kernel_launch(void* const* d_in, const int* in_sizes, int n_in,
                              void* d_out, int out_size, void* d_ws, size_t ws_size,
                              hipStream_t stream)
{
    const float*    x      = (const float*)d_in[0];
    const float*    top_w  = (const float*)d_in[2];
    const uint32_t* te     = (const uint32_t*)d_in[3];
    const float*    w_up   = (const float*)d_in[4];
    const float*    w_gate = (const float*)d_in[5];
    const float*    w_down = (const float*)d_in[6];
    float* out = (float*)d_out;
    char*  ws  = (char*)d_ws;

    int*   expert_off = (int*)(ws + OFF_EXP);
    int*   ntile_g    = (int*)(ws + OFF_NT);
    int*   tte        = (int*)(ws + OFF_TTE);
    int*   ttm        = (int*)(ws + OFF_TTM);
    int*   tok        = (int*)(ws + OFF_TOK);
    float* wgt        = (float*)(ws + OFF_WGT);
    bf16*  Xg         = (bf16*)(ws + OFF_XG);
    bf16*  H1         = (bf16*)(ws + OFF_H1);
    bf16*  WT         = (bf16*)(ws + OFF_WT);

    size_t wtcap = ws_size > (size_t)OFF_WT ? ws_size - (size_t)OFF_WT : 0;
    size_t perexp = (size_t)HID * FFN_ * 2;           // 4 MB bf16 per expert per matrix
    int g1 = (int)(wtcap / (2 * perexp));
    g1 = g1 >= 8 ? 8 : g1 >= 4 ? 4 : g1 >= 2 ? 2 : 1;
    int g2 = (int)(wtcap / perexp);
    g2 = g2 >= 8 ? 8 : g2 >= 4 ? 4 : g2 >= 2 ? 2 : 1;

    hipMemsetAsync(out, 0, (size_t)out_size * sizeof(float), stream);
    hipLaunchKernelGGL(route_kernel, dim3(1), dim3(512), 0, stream,
                       te, top_w, expert_off, ntile_g, tte, ttm, tok, wgt);
    hipLaunchKernelGGL(gather_kernel, dim3(NPAIR), dim3(256), 0, stream,
                       x, tok, Xg);

    for (int eb = 0; eb < NEXP; eb += g1) {
        bf16* wuT = WT;
        bf16* wgT = WT + (size_t)g1 * HID * FFN_;
        hipLaunchKernelGGL(transpose_bf16_2, dim3(FFN_ / 64, HID / 64, 2 * g1), dim3(256), 0, stream,
                           w_up + (size_t)eb * HID * FFN_, wuT,
                           w_gate + (size_t)eb * HID * FFN_, wgT, g1, HID, FFN_);
        hipLaunchKernelGGL(moe_upgate, dim3(FFN_ / 64, MAXTILE), dim3(256), 0, stream,
                           Xg, wuT, wgT, expert_off, ntile_g, tte, ttm, eb, g1, H1);
    }
    for (int eb = 0; eb < NEXP; eb += g2) {
        hipLaunchKernelGGL(transpose_bf16_2, dim3(HID / 64, FFN_ / 64, g2), dim3(256), 0, stream,
                           w_down + (size_t)eb * FFN_ * HID, WT,
                           w_down + (size_t)eb * FFN_ * HID, WT, g2, FFN_, HID);
        hipLaunchKernelGGL(moe_down, dim3(HID / 64, MAXTILE), dim3(256), 0, stream,
                           H1, WT, expert_off, ntile_g, tte, ttm, eb, g2, tok, wgt, out);
    }
}

// Round 7
// 194.906 us; speedup vs baseline: 1.3224x; 1.0027x over previous
//
#include <hip/hip_runtime.h>
#include <hip/hip_bf16.h>
#include <stdint.h>

#define T_TOK 2048
#define HID   1024
#define FFN_  2048
#define NEXP  8
#define NPAIR 4096   // T_TOK * top_k(2)
#define MAXTILE 40   // sum over experts of ceil(cnt/128) <= 32+8

typedef __bf16 bf16;
typedef __bf16 bf16x8 __attribute__((ext_vector_type(8)));
typedef __bf16 bf16x4 __attribute__((ext_vector_type(4)));
typedef float  f32x4  __attribute__((ext_vector_type(4)));
typedef unsigned int u32;

// ---- workspace layout (bytes) ----
#define OFF_EXP   0                                   // int[9]
#define OFF_NT    64                                  // int[1]
#define OFF_TTE   128                                 // int[64] tile->expert
#define OFF_TTM   512                                 // int[64] tile->m0
#define OFF_TOK   1024                                // int[NPAIR]
#define OFF_WGT   (OFF_TOK + 16384)                   // float[NPAIR]
#define OFF_XG    65536                               // bf16 [NPAIR][HID]   : 8 MB
#define OFF_H1    (OFF_XG + (size_t)NPAIR*HID*2)      // bf16 [NPAIR][FFN_]  : 16 MB

// async global->LDS, 16B per lane (dest = wave-uniform base + lane*16)
__device__ __forceinline__ void gld16(const void* g, void* l) {
    __builtin_amdgcn_global_load_lds(
        (const __attribute__((address_space(1))) u32*)g,
        (__attribute__((address_space(3))) u32*)l, 16, 0, 0);
}

// ---------------- routing: stable counting sort of pairs by expert ----------
__global__ void route_kernel(const uint32_t* __restrict__ te_raw,
                             const float* __restrict__ top_w,
                             int* __restrict__ expert_off,
                             int* __restrict__ ntile_g,
                             int* __restrict__ tte, int* __restrict__ ttm,
                             int* __restrict__ tok, float* __restrict__ wgt)
{
    __shared__ int counts[NEXP];
    __shared__ int offs[NEXP + 1];
    __shared__ int is64_s;
    int tid = threadIdx.x;           // 512 threads = 8 waves, wave w owns expert w
    int wv = tid >> 6, lane = tid & 63;
    if (tid == 0) {
        int z = 1;
        for (int i = 0; i < 64; ++i) if (te_raw[2*i + 1] != 0u) { z = 0; break; }
        is64_s = z;                  // int64 data has zero high words
    }
    __syncthreads();
    int is64 = is64_s;
    int cnt = 0;
    for (int base = 0; base < NPAIR; base += 64) {
        int p = base + lane;
        int eid = is64 ? (int)te_raw[2*p] : (int)te_raw[p];
        unsigned long long m = __ballot(eid == wv);
        cnt += __popcll(m);
    }
    if (lane == 0) counts[wv] = cnt;
    __syncthreads();
    if (tid == 0) {
        int s = 0;
        for (int e2 = 0; e2 < NEXP; ++e2) { offs[e2] = s; expert_off[e2] = s; s += counts[e2]; }
        offs[NEXP] = s; expert_off[NEXP] = s;
        int nt = 0;
        for (int e2 = 0; e2 < NEXP; ++e2)
            for (int m = offs[e2]; m < offs[e2 + 1]; m += 128) { tte[nt] = e2; ttm[nt] = m; ++nt; }
        *ntile_g = nt;
    }
    __syncthreads();
    int off = offs[wv];
    for (int base = 0; base < NPAIR; base += 64) {
        int p = base + lane;
        int eid = is64 ? (int)te_raw[2*p] : (int)te_raw[p];
        unsigned long long m = __ballot(eid == wv);
        if (eid == wv) {
            int pre = __popcll(m & ((1ull << lane) - 1ull));
            int s = off + pre;
            tok[s] = p >> 1;
            wgt[s] = top_w[p];
        }
        off += __popcll(m);
    }
}

// ---------------- gather x rows -> bf16 -------------------------------------
__global__ void gather_kernel(const float* __restrict__ x,
                              const int* __restrict__ tok,
                              bf16* __restrict__ Xg)
{
    int p = blockIdx.x;
    int t = tok[p];
    const float4* src = (const float4*)(x + (size_t)t * HID);
    float4 v = src[threadIdx.x];
    bf16x4 o;
    o[0] = (bf16)v.x; o[1] = (bf16)v.y; o[2] = (bf16)v.z; o[3] = (bf16)v.w;
    *(bf16x4*)(Xg + (size_t)p * HID + threadIdx.x * 4) = o;
}

// ---------------- GEMM1 (up then gate): single fp32 weight stream -----------
// tile 128(M) x 64(N), BK=64; A via gld16, B staged fp32->bf16 in registers
// (8 coalesced 256B wave-transactions per granule), swizzled ds_write_b128.
// GATE=0: H1 = silu(Xg@Wu).  GATE=1: H1 *= (Xg@Wg).
template<int GATE>
__global__ void __launch_bounds__(256)
moe_ug(const bf16* __restrict__ Xg, const float* __restrict__ W,
       const int* __restrict__ expert_off, const int* __restrict__ ntile_g,
       const int* __restrict__ tte, const int* __restrict__ ttm,
       bf16* __restrict__ H1)
{
    int ty = blockIdx.y;
    if (ty >= *ntile_g) return;
    int e = tte[ty];
    int m0 = ttm[ty];
    int p1 = expert_off[e + 1];
    int n0 = blockIdx.x * 64;
    __shared__ bf16 As[128 * 64];    // 16 KB
    __shared__ bf16 Bs[64 * 64];     // 8 KB -> 24 KB total
    const float* w = W + (size_t)e * HID * FFN_;
    int tid = threadIdx.x, lane = tid & 63, wv = tid >> 6;
    int wm = wv >> 1, wn = wv & 1;
    int l16 = lane & 15, lhi = lane >> 4;
    f32x4 acc[4][2] = {};

    // hoisted A staging pointers (advance +64 elems per K-step)
    const bf16* aptr[4]; u32 alds[4];
    #pragma unroll
    for (int c = 0; c < 4; ++c) {
        int g = c * 256 + tid;
        int r = g >> 3, pos = g & 7;
        int gr = m0 + r; if (gr >= p1) gr = p1 - 1;
        int gsrc = pos ^ (r & 7);
        aptr[c] = Xg + (size_t)gr * HID + gsrc * 8;
        alds[c] = g * 16;
    }
    // hoisted B staging: thread covers k-granules c0=wv and c0+4, f = lane
    int f = lane;
    int c0 = wv, c1 = wv + 4;
    const float* bsrc0 = w + (size_t)(c0 * 8) * FFN_ + n0 + f;
    const float* bsrc1 = w + (size_t)(c1 * 8) * FFN_ + n0 + f;
    u32 bw0 = f * 128 + ((u32)(c0 ^ (f & 7))) * 16;
    u32 bw1 = f * 128 + ((u32)(c1 ^ (f & 7))) * 16;
    // hoisted LDS fragment-read byte offsets (K-invariant)
    u32 aro[2][4], bro[2][2];
    #pragma unroll
    for (int ks = 0; ks < 2; ++ks) {
        #pragma unroll
        for (int fm = 0; fm < 4; ++fm) {
            int r = wm * 64 + fm * 16 + l16;
            aro[ks][fm] = r * 128 + ((u32)((ks * 4 + lhi) ^ (r & 7))) * 16;
        }
        #pragma unroll
        for (int fn = 0; fn < 2; ++fn) {
            int fr = wn * 32 + fn * 16 + l16;
            bro[ks][fn] = fr * 128 + ((u32)((ks * 4 + lhi) ^ (fr & 7))) * 16;
        }
    }

    for (int t = 0; t < HID / 64; ++t) {
        #pragma unroll
        for (int c = 0; c < 4; ++c) { gld16(aptr[c], (char*)As + alds[c]); aptr[c] += 64; }
        bf16x8 pb0, pb1;
        #pragma unroll
        for (int kk = 0; kk < 8; ++kk) pb0[kk] = (bf16)bsrc0[(size_t)kk * FFN_];
        #pragma unroll
        for (int kk = 0; kk < 8; ++kk) pb1[kk] = (bf16)bsrc1[(size_t)kk * FFN_];
        *(bf16x8*)((char*)Bs + bw0) = pb0;
        *(bf16x8*)((char*)Bs + bw1) = pb1;
        bsrc0 += 64 * FFN_; bsrc1 += 64 * FFN_;
        __syncthreads();
        #pragma unroll
        for (int ks = 0; ks < 2; ++ks) {
            bf16x8 af[4];
            #pragma unroll
            for (int fm = 0; fm < 4; ++fm)
                af[fm] = *(const bf16x8*)((char*)As + aro[ks][fm]);
            #pragma unroll
            for (int fn = 0; fn < 2; ++fn) {
                bf16x8 bb = *(const bf16x8*)((char*)Bs + bro[ks][fn]);
                #pragma unroll
                for (int fm = 0; fm < 4; ++fm)
                    acc[fm][fn] = __builtin_amdgcn_mfma_f32_16x16x32_bf16(af[fm], bb, acc[fm][fn], 0, 0, 0);
            }
        }
        __syncthreads();
    }
    #pragma unroll
    for (int fm = 0; fm < 4; ++fm)
    #pragma unroll
    for (int fn = 0; fn < 2; ++fn)
    #pragma unroll
    for (int rg = 0; rg < 4; ++rg) {
        int r = m0 + wm * 64 + fm * 16 + lhi * 4 + rg;
        if (r < p1) {
            int fc = n0 + wn * 32 + fn * 16 + l16;
            size_t idx = (size_t)r * FFN_ + fc;
            float v = acc[fm][fn][rg];
            if (GATE) {
                float s = (float)H1[idx];       // silu(u) from the up kernel
                H1[idx] = (bf16)(s * v);
            } else {
                H1[idx] = (bf16)(v / (1.f + __expf(-v)));
            }
        }
    }
}

// ---------------- GEMM2: out += (H1 @ Wdown) * wgt (atomic, 2 adds/elem) ----
__global__ void __launch_bounds__(256)
moe_down(const bf16* __restrict__ H1, const float* __restrict__ Wd,
         const int* __restrict__ expert_off, const int* __restrict__ ntile_g,
         const int* __restrict__ tte, const int* __restrict__ ttm,
         const int* __restrict__ tok, const float* __restrict__ wgt,
         float* __restrict__ out)
{
    int ty = blockIdx.y;
    if (ty >= *ntile_g) return;
    int e = tte[ty];
    int m0 = ttm[ty];
    int p1 = expert_off[e + 1];
    int n0 = blockIdx.x * 64;
    __shared__ bf16 As[128 * 64];    // 16 KB
    __shared__ bf16 Bs [64 * 64];    // 8 KB -> 24 KB total
    __shared__ float wgt_s[128];
    __shared__ int   tok_s[128];
    const float* wd = Wd + (size_t)e * FFN_ * HID;
    int tid = threadIdx.x, lane = tid & 63, wv = tid >> 6;
    int wm = wv >> 1, wn = wv & 1;
    int l16 = lane & 15, lhi = lane >> 4;
    if (tid < 128) {
        int r = m0 + tid;
        if (r < p1) { wgt_s[tid] = wgt[r]; tok_s[tid] = tok[r]; }
        else        { wgt_s[tid] = 0.f;    tok_s[tid] = 0; }
    }
    f32x4 acc[4][2] = {};

    const bf16* aptr[4]; u32 alds[4];
    #pragma unroll
    for (int c = 0; c < 4; ++c) {
        int g = c * 256 + tid;
        int r = g >> 3, pos = g & 7;
        int gr = m0 + r; if (gr >= p1) gr = p1 - 1;
        int gsrc = pos ^ (r & 7);
        aptr[c] = H1 + (size_t)gr * FFN_ + gsrc * 8;
        alds[c] = g * 16;
    }
    int f = lane;
    int c0 = wv, c1 = wv + 4;
    const float* bsrc0 = wd + (size_t)(c0 * 8) * HID + n0 + f;
    const float* bsrc1 = wd + (size_t)(c1 * 8) * HID + n0 + f;
    u32 bw0 = f * 128 + ((u32)(c0 ^ (f & 7))) * 16;
    u32 bw1 = f * 128 + ((u32)(c1 ^ (f & 7))) * 16;
    u32 aro[2][4], bro[2][2];
    #pragma unroll
    for (int ks = 0; ks < 2; ++ks) {
        #pragma unroll
        for (int fm = 0; fm < 4; ++fm) {
            int r = wm * 64 + fm * 16 + l16;
            aro[ks][fm] = r * 128 + ((u32)((ks * 4 + lhi) ^ (r & 7))) * 16;
        }
        #pragma unroll
        for (int fn = 0; fn < 2; ++fn) {
            int fr = wn * 32 + fn * 16 + l16;
            bro[ks][fn] = fr * 128 + ((u32)((ks * 4 + lhi) ^ (fr & 7))) * 16;
        }
    }

    for (int t = 0; t < FFN_ / 64; ++t) {
        #pragma unroll
        for (int c = 0; c < 4; ++c) { gld16(aptr[c], (char*)As + alds[c]); aptr[c] += 64; }
        bf16x8 pb0, pb1;
        #pragma unroll
        for (int kk = 0; kk < 8; ++kk) pb0[kk] = (bf16)bsrc0[(size_t)kk * HID];
        #pragma unroll
        for (int kk = 0; kk < 8; ++kk) pb1[kk] = (bf16)bsrc1[(size_t)kk * HID];
        *(bf16x8*)((char*)Bs + bw0) = pb0;
        *(bf16x8*)((char*)Bs + bw1) = pb1;
        bsrc0 += 64 * HID; bsrc1 += 64 * HID;
        __syncthreads();
        #pragma unroll
        for (int ks = 0; ks < 2; ++ks) {
            bf16x8 af[4];
            #pragma unroll
            for (int fm = 0; fm < 4; ++fm)
                af[fm] = *(const bf16x8*)((char*)As + aro[ks][fm]);
            #pragma unroll
            for (int fn = 0; fn < 2; ++fn) {
                bf16x8 bd = *(const bf16x8*)((char*)Bs + bro[ks][fn]);
                #pragma unroll
                for (int fm = 0; fm < 4; ++fm)
                    acc[fm][fn] = __builtin_amdgcn_mfma_f32_16x16x32_bf16(af[fm], bd, acc[fm][fn], 0, 0, 0);
            }
        }
        __syncthreads();
    }
    #pragma unroll
    for (int fm = 0; fm < 4; ++fm)
    #pragma unroll
    for (int fn = 0; fn < 2; ++fn)
    #pragma unroll
    for (int rg = 0; rg < 4; ++rg) {
        int rl = wm * 64 + fm * 16 + lhi * 4 + rg;
        if (m0 + rl < p1) {
            float v = acc[fm][fn][rg] * wgt_s[rl];
            atomicAdd(out + (size_t)tok_s[rl] * HID + n0 + wn * 32 + fn * 16 + l16, v);
        }
    }
}

extern "C" void kernel_launch(void* const* d_in, const int* in_sizes, int n_in,
                              void* d_out, int out_size, void* d_ws, size_t ws_size,
                              hipStream_t stream)
{
    const float*    x      = (const float*)d_in[0];
    const float*    top_w  = (const float*)d_in[2];
    const uint32_t* te     = (const uint32_t*)d_in[3];
    const float*    w_up   = (const float*)d_in[4];
    const float*    w_gate = (const float*)d_in[5];
    const float*    w_down = (const float*)d_in[6];
    float* out = (float*)d_out;
    char*  ws  = (char*)d_ws;

    int*   expert_off = (int*)(ws + OFF_EXP);
    int*   ntile_g    = (int*)(ws + OFF_NT);
    int*   tte        = (int*)(ws + OFF_TTE);
    int*   ttm        = (int*)(ws + OFF_TTM);
    int*   tok        = (int*)(ws + OFF_TOK);
    float* wgt        = (float*)(ws + OFF_WGT);
    bf16*  Xg         = (bf16*)(ws + OFF_XG);
    bf16*  H1         = (bf16*)(ws + OFF_H1);

    hipMemsetAsync(out, 0, (size_t)out_size * sizeof(float), stream);
    hipLaunchKernelGGL(route_kernel, dim3(1), dim3(512), 0, stream,
                       te, top_w, expert_off, ntile_g, tte, ttm, tok, wgt);
    hipLaunchKernelGGL(gather_kernel, dim3(NPAIR), dim3(256), 0, stream,
                       x, tok, Xg);
    hipLaunchKernelGGL((moe_ug<0>), dim3(FFN_ / 64, MAXTILE), dim3(256), 0, stream,
                       Xg, w_up, expert_off, ntile_g, tte, ttm, H1);
    hipLaunchKernelGGL((moe_ug<1>), dim3(FFN_ / 64, MAXTILE), dim3(256), 0, stream,
                       Xg, w_gate, expert_off, ntile_g, tte, ttm, H1);
    hipLaunchKernelGGL(moe_down, dim3(HID / 64, MAXTILE), dim3(256), 0, stream,
                       H1, w_down, expert_off, ntile_g, tte, ttm, tok, wgt, out);
}